// Round 2
// baseline (1150.047 us; speedup 1.0000x reference)
//
#include <hip/hip_runtime.h>

// ShootingBlock: only the u-trajectory is observable. theta/bias are fixed
// functions of the initial params (Mbar/Mbar_b identity), du = relu(u)@theta^T
// + bias is independent of x/p -> integrate u only.
//
// R2 changes vs R1 (850 us):
//  - theta: split-K x8 (512 blocks) -> partials (alias kA) -> combine.
//    R1 grid was 64 blocks @ 52 us, pure latency.
//  - feval: BM=128xBN=64, 8x4 microtile (32 FMA / 3 ds_read_b128 per kk),
//    register-double-buffered LDS: prefetch tile k+1 (global->regs) before
//    compute of tile k, stage regs->LDS[other buf] after. Hides global
//    latency under the 2048-cyc compute phase at grid=256 (1 block/CU).

namespace {

constexpr int KP = 1024;
constexpr int D  = 512;
constexpr int M  = 4096;
constexpr int T  = 6;

// feval tiling
constexpr int BM = 128, BN = 64, BK = 32;
constexpr int NT  = D / BK;       // 16 K-tiles
constexpr int LDA = BM + 4;       // 132 floats (528 B, %16==0): b128-aligned rows
constexpr int LDB = BN + 4;       // 68 floats  (272 B, %16==0)

// theta tiling
constexpr int TBM = 64, TBN = 64, TBK = 32;
constexpr int TLD = TBM + 4;
constexpr int KSPLIT = 8;         // 8 chunks of 128

// ---------------------------------------------------------------------------
// theta partial: part[bz][d][e] = sum_{k in chunk bz} ps[k][d]*relu(xs[k][e])
// ---------------------------------------------------------------------------
__global__ __launch_bounds__(256) void theta_partial_kernel(
    const float* __restrict__ xs, const float* __restrict__ ps,
    float* __restrict__ part) {
  __shared__ float As[TBK][TLD];
  __shared__ float Bs[TBK][TLD];
  const int d0 = blockIdx.x * TBM;
  const int e0 = blockIdx.y * TBN;
  const int kb = blockIdx.z * (KP / KSPLIT);
  const int t  = threadIdx.x;
  const int tx = t & 15, ty = t >> 4;
  float acc[4][4] = {};

  for (int k0 = kb; k0 < kb + KP / KSPLIT; k0 += TBK) {
#pragma unroll
    for (int p = 0; p < 2; ++p) {
      const int idx = t + p * 256;
      const int c4  = idx & 15;
      const int row = idx >> 4;
      float4 av = *(const float4*)(ps + (size_t)(k0 + row) * D + d0 + c4 * 4);
      *(float4*)&As[row][c4 * 4] = av;
      float4 bv = *(const float4*)(xs + (size_t)(k0 + row) * D + e0 + c4 * 4);
      bv.x = fmaxf(bv.x, 0.f); bv.y = fmaxf(bv.y, 0.f);
      bv.z = fmaxf(bv.z, 0.f); bv.w = fmaxf(bv.w, 0.f);
      *(float4*)&Bs[row][c4 * 4] = bv;
    }
    __syncthreads();
#pragma unroll
    for (int kk = 0; kk < TBK; ++kk) {
      const float4 a4 = *(const float4*)&As[kk][ty * 4];
      const float4 b4 = *(const float4*)&Bs[kk][tx * 4];
      const float a[4] = {a4.x, a4.y, a4.z, a4.w};
      const float b[4] = {b4.x, b4.y, b4.z, b4.w};
#pragma unroll
      for (int i = 0; i < 4; ++i)
#pragma unroll
        for (int j = 0; j < 4; ++j)
          acc[i][j] = fmaf(a[i], b[j], acc[i][j]);
    }
    __syncthreads();
  }
  float* dst = part + (size_t)blockIdx.z * D * D;
#pragma unroll
  for (int i = 0; i < 4; ++i) {
    float4 v;
    v.x = acc[i][0]; v.y = acc[i][1]; v.z = acc[i][2]; v.w = acc[i][3];
    *(float4*)(dst + (size_t)(d0 + ty * 4 + i) * D + e0 + tx * 4) = v;
  }
}

// theta[i] = -(sum over KSPLIT partials)
__global__ __launch_bounds__(256) void theta_combine_kernel(
    const float* __restrict__ part, float* __restrict__ theta) {
  const size_t i = (size_t)blockIdx.x * 256 + threadIdx.x;  // float4 index
  float4 s = ((const float4*)part)[i];
#pragma unroll
  for (int z = 1; z < KSPLIT; ++z) {
    const float4 v = ((const float4*)(part + (size_t)z * D * D))[i];
    s.x += v.x; s.y += v.y; s.z += v.z; s.w += v.w;
  }
  s.x = -s.x; s.y = -s.y; s.z = -s.z; s.w = -s.w;
  ((float4*)theta)[i] = s;
}

// ---------------------------------------------------------------------------
__global__ __launch_bounds__(256) void bias_kernel(const float* __restrict__ ps,
                                                   float* __restrict__ bias) {
  __shared__ float part[4][64];
  const int dc = threadIdx.x & 63;
  const int sl = threadIdx.x >> 6;
  const int d  = blockIdx.x * 64 + dc;
  float s = 0.f;
  for (int k = sl * 256; k < sl * 256 + 256; ++k) s += ps[(size_t)k * D + d];
  part[sl][dc] = s;
  __syncthreads();
  if (threadIdx.x < 64) {
    const int c = threadIdx.x;
    bias[blockIdx.x * 64 + c] =
        -(part[0][c] + part[1][c] + part[2][c] + part[3][c]);
  }
}

__global__ __launch_bounds__(256) void copy_kernel(const float* __restrict__ src,
                                                   float* __restrict__ dst) {
  const size_t i = (size_t)blockIdx.x * 256 + threadIdx.x;
  ((float4*)dst)[i] = ((const float4*)src)[i];
}

// ---------------------------------------------------------------------------
// RK4 stage GEMM: C[m][d] = bias[d] + sum_e relu(Yin[m][e]) * theta[d][e]
//   MODE 0: Yin=u,             kout=C, acc=C
//   MODE 1/2: Yin=u+0.5*dt*kp, kout=C, acc+=2C
//   MODE 3: Yin=u+dt*kp,       unew = u + dt/6*(acc+C)
// Tiling: 128x64x32, 256 threads, 8x4 microtile, double-buffered LDS with
// register prefetch. A/B staged transposed ([e][m]) for b128 fragment reads.
// ---------------------------------------------------------------------------
template <int MODE>
__global__ __launch_bounds__(256) void feval_kernel(const float* __restrict__ u,
                                                    const float* __restrict__ kprev,
                                                    const float* __restrict__ theta,
                                                    const float* __restrict__ bias,
                                                    const float* __restrict__ bt,
                                                    int step,
                                                    float* __restrict__ kout,
                                                    float* __restrict__ acc,
                                                    float* __restrict__ unew) {
  __shared__ float As[2][BK][LDA];
  __shared__ float Bs[2][BK][LDB];
  const float dt = bt[step + 1] - bt[step];
  const float c  = (MODE == 0) ? 0.f : (MODE == 3 ? dt : 0.5f * dt);
  const int m0 = blockIdx.x * BM;
  const int n0 = blockIdx.y * BN;
  const int t  = threadIdx.x;
  const int tx = t & 15, ty = t >> 4;
  const int am  = t >> 3;   // 0..31 (base row; +32p)
  const int ae4 = t & 7;    // float4-column within the 32-wide K slab

  float accr[8][4] = {};
  float4 ar[4], br[2];

  auto prefetch = [&](int kt) {
    const int e0 = kt * BK;
#pragma unroll
    for (int p = 0; p < 4; ++p) {
      const int m = am + p * 32;
      const size_t off = (size_t)(m0 + m) * D + e0 + ae4 * 4;
      float4 yv = *(const float4*)(u + off);
      if constexpr (MODE != 0) {
        const float4 kv = *(const float4*)(kprev + off);
        yv.x = fmaf(c, kv.x, yv.x); yv.y = fmaf(c, kv.y, yv.y);
        yv.z = fmaf(c, kv.z, yv.z); yv.w = fmaf(c, kv.w, yv.w);
      }
      yv.x = fmaxf(yv.x, 0.f); yv.y = fmaxf(yv.y, 0.f);
      yv.z = fmaxf(yv.z, 0.f); yv.w = fmaxf(yv.w, 0.f);
      ar[p] = yv;
    }
#pragma unroll
    for (int p = 0; p < 2; ++p) {
      const int n = am + p * 32;
      br[p] = *(const float4*)(theta + (size_t)(n0 + n) * D + e0 + ae4 * 4);
    }
  };

  auto stage = [&](int buf) {
#pragma unroll
    for (int p = 0; p < 4; ++p) {
      const int m = am + p * 32;
      As[buf][ae4 * 4 + 0][m] = ar[p].x;
      As[buf][ae4 * 4 + 1][m] = ar[p].y;
      As[buf][ae4 * 4 + 2][m] = ar[p].z;
      As[buf][ae4 * 4 + 3][m] = ar[p].w;
    }
#pragma unroll
    for (int p = 0; p < 2; ++p) {
      const int n = am + p * 32;
      Bs[buf][ae4 * 4 + 0][n] = br[p].x;
      Bs[buf][ae4 * 4 + 1][n] = br[p].y;
      Bs[buf][ae4 * 4 + 2][n] = br[p].z;
      Bs[buf][ae4 * 4 + 3][n] = br[p].w;
    }
  };

  prefetch(0);
  stage(0);
  __syncthreads();

  for (int kt = 0; kt < NT; ++kt) {
    const int buf = kt & 1;
    if (kt + 1 < NT) prefetch(kt + 1);  // global loads in flight during compute
#pragma unroll
    for (int kk = 0; kk < BK; ++kk) {
      const float4 a0 = *(const float4*)&As[buf][kk][ty * 8];
      const float4 a1 = *(const float4*)&As[buf][kk][ty * 8 + 4];
      const float4 b4 = *(const float4*)&Bs[buf][kk][tx * 4];
      const float a[8] = {a0.x, a0.y, a0.z, a0.w, a1.x, a1.y, a1.z, a1.w};
      const float b[4] = {b4.x, b4.y, b4.z, b4.w};
#pragma unroll
      for (int i = 0; i < 8; ++i)
#pragma unroll
        for (int j = 0; j < 4; ++j)
          accr[i][j] = fmaf(a[i], b[j], accr[i][j]);
    }
    if (kt + 1 < NT) stage(buf ^ 1);
    __syncthreads();
  }

  const float4 bv = *(const float4*)(bias + n0 + tx * 4);
  const float bb[4] = {bv.x, bv.y, bv.z, bv.w};
#pragma unroll
  for (int i = 0; i < 8; ++i) {
    const size_t off = (size_t)(m0 + ty * 8 + i) * D + n0 + tx * 4;
    float4 C;
    C.x = accr[i][0] + bb[0];
    C.y = accr[i][1] + bb[1];
    C.z = accr[i][2] + bb[2];
    C.w = accr[i][3] + bb[3];
    if constexpr (MODE == 0) {
      *(float4*)(kout + off) = C;
      *(float4*)(acc + off)  = C;
    } else if constexpr (MODE == 1 || MODE == 2) {
      *(float4*)(kout + off) = C;
      float4 a = *(const float4*)(acc + off);
      a.x = fmaf(2.f, C.x, a.x); a.y = fmaf(2.f, C.y, a.y);
      a.z = fmaf(2.f, C.z, a.z); a.w = fmaf(2.f, C.w, a.w);
      *(float4*)(acc + off) = a;
    } else {
      const float4 uv = *(const float4*)(u + off);
      const float4 av = *(const float4*)(acc + off);
      const float s6 = dt * (1.f / 6.f);
      float4 o;
      o.x = fmaf(s6, av.x + C.x, uv.x);
      o.y = fmaf(s6, av.y + C.y, uv.y);
      o.z = fmaf(s6, av.z + C.z, uv.z);
      o.w = fmaf(s6, av.w + C.w, uv.w);
      *(float4*)(unew + off) = o;
    }
  }
}

}  // namespace

extern "C" void kernel_launch(void* const* d_in, const int* in_sizes, int n_in,
                              void* d_out, int out_size, void* d_ws, size_t ws_size,
                              hipStream_t stream) {
  (void)in_sizes; (void)n_in; (void)out_size; (void)ws_size;
  const float* xs  = (const float*)d_in[0];  // x_params (K,1,D)
  const float* ps  = (const float*)d_in[1];  // p_params (K,1,D)
  // d_in[2] Mbar, d_in[3] Mbar_b: identity -> inv() no-op
  const float* inp = (const float*)d_in[4];  // (M,1,D)
  const float* bt  = (const float*)d_in[5];  // (T,)
  float* out = (float*)d_out;                // (T, M, 1, D)
  float* ws  = (float*)d_ws;

  float* theta = ws;                               // D*D floats (1 MB)
  float* bias  = theta + (size_t)D * D;            // 512
  float* kA    = bias + 512;                       // M*D (8 MB)
  float* kB    = kA + (size_t)M * D;               // M*D
  float* acc   = kB + (size_t)M * D;               // M*D  (total ~26.2 MB)
  float* part  = kA;  // theta partials (8 MB) alias kA: used before any feval

  theta_partial_kernel<<<dim3(D / TBM, D / TBN, KSPLIT), 256, 0, stream>>>(xs, ps, part);
  theta_combine_kernel<<<(D * D) / (4 * 256), 256, 0, stream>>>(part, theta);
  bias_kernel<<<D / 64, 256, 0, stream>>>(ps, bias);
  copy_kernel<<<(M * D) / (4 * 256), 256, 0, stream>>>(inp, out);

  const dim3 grid(M / BM, D / BN);
  for (int s = 0; s < T - 1; ++s) {
    float* u     = out + (size_t)s * M * D;
    float* unext = out + (size_t)(s + 1) * M * D;
    feval_kernel<0><<<grid, 256, 0, stream>>>(u, nullptr, theta, bias, bt, s, kA, acc, nullptr);
    feval_kernel<1><<<grid, 256, 0, stream>>>(u, kA, theta, bias, bt, s, kB, acc, nullptr);
    feval_kernel<2><<<grid, 256, 0, stream>>>(u, kB, theta, bias, bt, s, kA, acc, nullptr);
    feval_kernel<3><<<grid, 256, 0, stream>>>(u, kA, theta, bias, bt, s, nullptr, acc, unext);
  }
}

// Round 3
// 851.829 us; speedup vs baseline: 1.3501x; 1.3501x over previous
//
#include <hip/hip_runtime.h>

// ShootingBlock: only the u-trajectory is observable (traj records y[2K:] and
// du = relu(u)@theta^T + bias is self-contained; Mbar/Mbar_b are identity).
//
// R3: m97-style fp32 GEMM. All feval operands live pre-transposed in global
// ([e][m] / [e][d]) so A and B tiles stage via pure global_load_lds DMA.
// Each stage's epilogue produces the NEXT stage's A operand:
//   YinT_{i+1} = relu(u + c_{i+1} k_{i+1})^T   (transposed through LDS).
// K-loop: 2 ds_read_b128 + 16 v_fma per kk, double-buffered LDS, DMA for
// tile kt+1 in flight during compute of kt.

namespace {

constexpr int KP = 1024;
constexpr int D  = 512;
constexpr int M  = 4096;

constexpr int BM = 64, BN = 64, BK = 32;
constexpr int NT = D / BK;  // 16

__device__ __forceinline__ void glds16(const float* g, float* l) {
  __builtin_amdgcn_global_load_lds(
      (__attribute__((address_space(1))) const void*)g,
      (__attribute__((address_space(3))) void*)l, 16, 0, 0);
}

// ---------------------------------------------------------------------------
// part[z][e][d] = sum_{k in chunk z} relu(xs[k][e]) * ps[k][d]   (thetaT order)
// ---------------------------------------------------------------------------
constexpr int TBK = 32;
constexpr int TLD = 68;
constexpr int KSPLIT = 8;

__global__ __launch_bounds__(256) void theta_partial_kernel(
    const float* __restrict__ xs, const float* __restrict__ ps,
    float* __restrict__ part) {
  __shared__ float As[TBK][TLD];  // relu(xs), e-block
  __shared__ float Bs[TBK][TLD];  // ps, d-block
  const int e0 = blockIdx.x * 64;
  const int d0 = blockIdx.y * 64;
  const int kb = blockIdx.z * (KP / KSPLIT);
  const int t  = threadIdx.x;
  const int tx = t & 15, ty = t >> 4;
  float acc[4][4] = {};

  for (int k0 = kb; k0 < kb + KP / KSPLIT; k0 += TBK) {
#pragma unroll
    for (int p = 0; p < 2; ++p) {
      const int idx = t + p * 256;
      const int c4  = idx & 15;
      const int row = idx >> 4;
      float4 av = *(const float4*)(xs + (size_t)(k0 + row) * D + e0 + c4 * 4);
      av.x = fmaxf(av.x, 0.f); av.y = fmaxf(av.y, 0.f);
      av.z = fmaxf(av.z, 0.f); av.w = fmaxf(av.w, 0.f);
      *(float4*)&As[row][c4 * 4] = av;
      const float4 bv = *(const float4*)(ps + (size_t)(k0 + row) * D + d0 + c4 * 4);
      *(float4*)&Bs[row][c4 * 4] = bv;
    }
    __syncthreads();
#pragma unroll
    for (int kk = 0; kk < TBK; ++kk) {
      const float4 a4 = *(const float4*)&As[kk][ty * 4];
      const float4 b4 = *(const float4*)&Bs[kk][tx * 4];
      const float a[4] = {a4.x, a4.y, a4.z, a4.w};
      const float b[4] = {b4.x, b4.y, b4.z, b4.w};
#pragma unroll
      for (int i = 0; i < 4; ++i)
#pragma unroll
        for (int j = 0; j < 4; ++j)
          acc[i][j] = fmaf(a[i], b[j], acc[i][j]);
    }
    __syncthreads();
  }
  float* dst = part + (size_t)blockIdx.z * D * D;
#pragma unroll
  for (int i = 0; i < 4; ++i) {
    float4 v;
    v.x = acc[i][0]; v.y = acc[i][1]; v.z = acc[i][2]; v.w = acc[i][3];
    *(float4*)(dst + (size_t)(e0 + ty * 4 + i) * D + d0 + tx * 4) = v;
  }
}

__global__ __launch_bounds__(256) void theta_combine_kernel(
    const float* __restrict__ part, float* __restrict__ thetaT) {
  const size_t i = (size_t)blockIdx.x * 256 + threadIdx.x;  // float4 index
  float4 s = ((const float4*)part)[i];
#pragma unroll
  for (int z = 1; z < KSPLIT; ++z) {
    const float4 v = ((const float4*)(part + (size_t)z * D * D))[i];
    s.x += v.x; s.y += v.y; s.z += v.z; s.w += v.w;
  }
  s.x = -s.x; s.y = -s.y; s.z = -s.z; s.w = -s.w;
  ((float4*)thetaT)[i] = s;
}

__global__ __launch_bounds__(256) void bias_kernel(const float* __restrict__ ps,
                                                   float* __restrict__ bias) {
  __shared__ float part[4][64];
  const int dc = threadIdx.x & 63;
  const int sl = threadIdx.x >> 6;
  const int d  = blockIdx.x * 64 + dc;
  float s = 0.f;
  for (int k = sl * 256; k < sl * 256 + 256; ++k) s += ps[(size_t)k * D + d];
  part[sl][dc] = s;
  __syncthreads();
  if (threadIdx.x < 64) {
    const int c = threadIdx.x;
    bias[blockIdx.x * 64 + c] =
        -(part[0][c] + part[1][c] + part[2][c] + part[3][c]);
  }
}

// ---------------------------------------------------------------------------
// out0 = inp (copy); uT = inp^T; yin = relu(inp)^T.  64x64 tiles.
// ---------------------------------------------------------------------------
__global__ __launch_bounds__(256) void init_kernel(const float* __restrict__ inp,
                                                   float* __restrict__ out0,
                                                   float* __restrict__ uT,
                                                   float* __restrict__ yin) {
  __shared__ float Tr[64][68];
  const int t  = threadIdx.x;
  const int m0 = blockIdx.x * 64, e0 = blockIdx.y * 64;
  const int cc = t & 15;
#pragma unroll
  for (int p = 0; p < 4; ++p) {
    const int row = (t >> 4) + p * 16;  // m row
    const size_t g = (size_t)(m0 + row) * D + e0 + cc * 4;
    const float4 v = *(const float4*)(inp + g);
    *(float4*)(out0 + g) = v;
    Tr[cc * 4 + 0][row] = v.x;
    Tr[cc * 4 + 1][row] = v.y;
    Tr[cc * 4 + 2][row] = v.z;
    Tr[cc * 4 + 3][row] = v.w;
  }
  __syncthreads();
#pragma unroll
  for (int p = 0; p < 4; ++p) {
    const int row = (t >> 4) + p * 16;  // e row
    const float4 v = *(const float4*)&Tr[row][cc * 4];
    const size_t g = (size_t)(e0 + row) * M + m0 + cc * 4;
    *(float4*)(uT + g) = v;
    float4 y;
    y.x = fmaxf(v.x, 0.f); y.y = fmaxf(v.y, 0.f);
    y.z = fmaxf(v.z, 0.f); y.w = fmaxf(v.w, 0.f);
    *(float4*)(yin + g) = y;
  }
}

// ---------------------------------------------------------------------------
// feval<MODE>: k = YinT^T @ thetaT + bias  (C[m][n] = sum_e YinT[e][m]*thetaT[e][n])
//  MODE 0: acc = k;       yinWr = relu(u + dt/2 k)^T
//  MODE 1: acc += 2k;     yinWr = relu(u + dt/2 k)^T
//  MODE 2: acc += 2k;     yinWr = relu(u + dt   k)^T
//  MODE 3: unew = u + dt/6 (acc + k) -> outStd; uTout = unew^T; yinWr = relu(unew)^T
// ---------------------------------------------------------------------------
template <int MODE>
__global__ __launch_bounds__(256) void feval_kernel(
    const float* __restrict__ yinRd, const float* __restrict__ thetaT,
    const float* __restrict__ bias, const float* __restrict__ bt, int step,
    const float* __restrict__ uStd, const float* __restrict__ uT,
    float* __restrict__ acc, float* __restrict__ yinWr,
    float* __restrict__ outStd, float* __restrict__ uTout) {
  __shared__ float pool[8448];                     // 33 KB
  float (*As)[64] = (float(*)[64])pool;            // [2*BK][64] (buf*BK + kk)
  float (*Bs)[64] = (float(*)[64])(pool + 4096);
  float (*Tr)[68] = (float(*)[68])pool;            // epilogue transpose (overlay)

  const int t    = threadIdx.x;
  const int tx   = t & 15, ty = t >> 4;
  const int w    = t >> 6;
  const int lane = t & 63;
  const int er   = lane >> 4;        // 0..3
  const int lc   = (lane & 15) * 4;  // float col within 64-wide row
  const int m0   = blockIdx.x * BM;
  const int n0   = blockIdx.y * BN;
  const float dt = bt[step + 1] - bt[step];

  auto dma = [&](int buf, int kt) {
    const int e0 = kt * BK;
#pragma unroll
    for (int r = 0; r < 2; ++r) {
      const int el = w * 8 + r * 4;  // wave-uniform base row in tile
      glds16(yinRd + (size_t)(e0 + el + er) * M + m0 + lc, &As[buf * BK + el][0]);
      glds16(thetaT + (size_t)(e0 + el + er) * D + n0 + lc, &Bs[buf * BK + el][0]);
    }
  };

  float accr[4][4] = {};
  dma(0, 0);
  __syncthreads();

  for (int kt = 0; kt < NT; ++kt) {
    const int buf = kt & 1;
    if (kt + 1 < NT) dma(buf ^ 1, kt + 1);  // async, lands before next barrier
#pragma unroll
    for (int kk = 0; kk < BK; ++kk) {
      const float4 a4 = *(const float4*)&As[buf * BK + kk][ty * 4];
      const float4 b4 = *(const float4*)&Bs[buf * BK + kk][tx * 4];
      const float a[4] = {a4.x, a4.y, a4.z, a4.w};
      const float b[4] = {b4.x, b4.y, b4.z, b4.w};
#pragma unroll
      for (int i = 0; i < 4; ++i)
#pragma unroll
        for (int j = 0; j < 4; ++j)
          accr[i][j] = fmaf(a[i], b[j], accr[i][j]);
    }
    __syncthreads();  // drains vmcnt (incl. DMA for kt+1) + LDS reads of buf
  }

  const float4 bv = *(const float4*)(bias + n0 + tx * 4);
  const float bb[4] = {bv.x, bv.y, bv.z, bv.w};
  float k[4][4];
#pragma unroll
  for (int i = 0; i < 4; ++i)
#pragma unroll
    for (int j = 0; j < 4; ++j) k[i][j] = accr[i][j] + bb[j];

  if constexpr (MODE <= 2) {
#pragma unroll
    for (int i = 0; i < 4; ++i) {
      const size_t off = (size_t)(m0 + ty * 4 + i) * D + n0 + tx * 4;
      float4 kv;
      kv.x = k[i][0]; kv.y = k[i][1]; kv.z = k[i][2]; kv.w = k[i][3];
      if constexpr (MODE == 0) {
        *(float4*)(acc + off) = kv;
      } else {
        float4 a = *(const float4*)(acc + off);
        a.x = fmaf(2.f, kv.x, a.x); a.y = fmaf(2.f, kv.y, a.y);
        a.z = fmaf(2.f, kv.z, a.z); a.w = fmaf(2.f, kv.w, a.w);
        *(float4*)(acc + off) = a;
      }
    }
    // transpose k -> Tr[n][m] (swizzled col4 ^= row&3)
#pragma unroll
    for (int j = 0; j < 4; ++j) {
      float4 v;
      v.x = k[0][j]; v.y = k[1][j]; v.z = k[2][j]; v.w = k[3][j];
      *(float4*)&Tr[tx * 4 + j][(ty ^ j) * 4] = v;
    }
    __syncthreads();
    const float cn = (MODE == 2) ? dt : 0.5f * dt;
    const int cc = t & 15;
#pragma unroll
    for (int p = 0; p < 4; ++p) {
      const int row = (t >> 4) + p * 16;
      const float4 kv = *(const float4*)&Tr[row][(cc ^ (row & 3)) * 4];
      const size_t g = (size_t)(n0 + row) * M + m0 + cc * 4;
      const float4 uv = *(const float4*)(uT + g);
      float4 y;
      y.x = fmaxf(fmaf(cn, kv.x, uv.x), 0.f);
      y.y = fmaxf(fmaf(cn, kv.y, uv.y), 0.f);
      y.z = fmaxf(fmaf(cn, kv.z, uv.z), 0.f);
      y.w = fmaxf(fmaf(cn, kv.w, uv.w), 0.f);
      *(float4*)(yinWr + g) = y;
    }
  } else {
    const float s6 = dt * (1.f / 6.f);
    float un[4][4];
#pragma unroll
    for (int i = 0; i < 4; ++i) {
      const size_t off = (size_t)(m0 + ty * 4 + i) * D + n0 + tx * 4;
      const float4 uv = *(const float4*)(uStd + off);
      const float4 av = *(const float4*)(acc + off);
      float4 o;
      o.x = fmaf(s6, av.x + k[i][0], uv.x);
      o.y = fmaf(s6, av.y + k[i][1], uv.y);
      o.z = fmaf(s6, av.z + k[i][2], uv.z);
      o.w = fmaf(s6, av.w + k[i][3], uv.w);
      *(float4*)(outStd + off) = o;
      un[i][0] = o.x; un[i][1] = o.y; un[i][2] = o.z; un[i][3] = o.w;
    }
#pragma unroll
    for (int j = 0; j < 4; ++j) {
      float4 v;
      v.x = un[0][j]; v.y = un[1][j]; v.z = un[2][j]; v.w = un[3][j];
      *(float4*)&Tr[tx * 4 + j][(ty ^ j) * 4] = v;
    }
    __syncthreads();
    const int cc = t & 15;
#pragma unroll
    for (int p = 0; p < 4; ++p) {
      const int row = (t >> 4) + p * 16;
      const float4 v = *(const float4*)&Tr[row][(cc ^ (row & 3)) * 4];
      const size_t g = (size_t)(n0 + row) * M + m0 + cc * 4;
      *(float4*)(uTout + g) = v;
      float4 y;
      y.x = fmaxf(v.x, 0.f); y.y = fmaxf(v.y, 0.f);
      y.z = fmaxf(v.z, 0.f); y.w = fmaxf(v.w, 0.f);
      *(float4*)(yinWr + g) = y;
    }
  }
}

}  // namespace

extern "C" void kernel_launch(void* const* d_in, const int* in_sizes, int n_in,
                              void* d_out, int out_size, void* d_ws, size_t ws_size,
                              hipStream_t stream) {
  (void)in_sizes; (void)n_in; (void)out_size; (void)ws_size;
  const float* xs  = (const float*)d_in[0];  // x_params (K,1,D)
  const float* ps  = (const float*)d_in[1];  // p_params (K,1,D)
  // d_in[2] Mbar, d_in[3] Mbar_b: identity -> inv() no-op
  const float* inp = (const float*)d_in[4];  // (M,1,D)
  const float* bt  = (const float*)d_in[5];  // (T,)
  float* out = (float*)d_out;                // (T, M, 1, D)
  float* ws  = (float*)d_ws;

  float* thetaT = ws;                           // D*D floats (1 MB), [e][d]
  float* bias   = thetaT + (size_t)D * D;       // 512
  float* uT     = bias + 512;                   // D*M (8 MB), [e][m]
  float* yinA   = uT + (size_t)D * M;           // D*M
  float* yinB   = yinA + (size_t)D * M;         // D*M
  float* acc    = yinB + (size_t)D * M;         // M*D   (total ~34.7 MB)
  float* part   = acc;  // theta partials (8*D*D = M*D floats) alias acc

  theta_partial_kernel<<<dim3(8, 8, KSPLIT), 256, 0, stream>>>(xs, ps, part);
  theta_combine_kernel<<<(D * D) / (4 * 256), 256, 0, stream>>>(part, thetaT);
  bias_kernel<<<D / 64, 256, 0, stream>>>(ps, bias);
  init_kernel<<<dim3(M / 64, D / 64), 256, 0, stream>>>(inp, out, uT, yinA);

  const dim3 grid(M / BM, D / BN);
  for (int s = 0; s < 5; ++s) {
    float* u     = out + (size_t)s * M * D;
    float* unext = out + (size_t)(s + 1) * M * D;
    feval_kernel<0><<<grid, 256, 0, stream>>>(yinA, thetaT, bias, bt, s,
                                              nullptr, uT, acc, yinB, nullptr, nullptr);
    feval_kernel<1><<<grid, 256, 0, stream>>>(yinB, thetaT, bias, bt, s,
                                              nullptr, uT, acc, yinA, nullptr, nullptr);
    feval_kernel<2><<<grid, 256, 0, stream>>>(yinA, thetaT, bias, bt, s,
                                              nullptr, uT, acc, yinB, nullptr, nullptr);
    feval_kernel<3><<<grid, 256, 0, stream>>>(yinB, thetaT, bias, bt, s,
                                              u, nullptr, acc, yinA, unext, uT);
  }
}